// Round 3
// baseline (8052.210 us; speedup 1.0000x reference)
//
#include <hip/hip_runtime.h>
#include <hip/hip_bf16.h>
#include <hip/hip_cooperative_groups.h>
#include <math.h>

namespace cg = cooperative_groups;

typedef unsigned short u16;
typedef __attribute__((ext_vector_type(8))) __bf16 bf16x8;
typedef __attribute__((ext_vector_type(4))) float f32x4;

#define LSTM_L 200
#define LSTM_B 2048
#define LSTM_HIN 64
#define LSTM_H 256
#define NCLUST 64
#define HALF_BETA 0.05f

#define NCH0 10                    // (64+256)/32 k-chunks, layer0
#define NCH1 16                    // (256+256)/32, layer1
#define W0_U16 (NCH0 * 4 * 64 * 8) // 20480 u16 = 40 KB per n-slice
#define W1_U16 (NCH1 * 4 * 64 * 8) // 32768 u16 = 64 KB per n-slice
#define LDS_BYTES ((W0_U16 + W1_U16) * 2) // 106496 B

// ---------------------------------------------------------------------------
// Pack weights into MFMA-fragment order, per n-slice:
// Wp[nb][c][g][lane][e] = W[j][k], j = g*256 + nb*16 + (lane&15),
// k = c*32 + (lane>>4)*8 + e;  W = [Wih | Whh] k-concatenated, bf16.
// ---------------------------------------------------------------------------
template<int KIN>
__global__ __launch_bounds__(256) void pack_frag(
    const float* __restrict__ Wih, const float* __restrict__ Whh,
    u16* __restrict__ Wp)
{
    constexpr int NCH = (KIN + LSTM_H) / 32;
    const int total = 16 * NCH * 4 * 64 * 8;
    for (int i = blockIdx.x * 256 + threadIdx.x; i < total; i += gridDim.x * 256) {
        const int e    = i & 7;
        const int lane = (i >> 3) & 63;
        const int g    = (i >> 9) & 3;
        const int rest = i >> 11;
        const int c    = rest % NCH;
        const int nb   = rest / NCH;
        const int j = g * 256 + nb * 16 + (lane & 15);
        const int k = c * 32 + ((lane >> 4) << 3) + e;
        const float v = (k < KIN) ? Wih[(size_t)j * KIN + k]
                                  : Whh[(size_t)j * LSTM_H + (k - KIN)];
        const __bf16 b = (__bf16)v;
        Wp[i] = __builtin_bit_cast(u16, b);
    }
}

// ---------------------------------------------------------------------------
// Persistent 2-layer LSTM. 256 blocks (16 mb x 16 nb), 512 threads = 8 waves.
// Wave = 16 batch rows x (16 h-cols x 4 gates). Weights LDS-resident
// (frag-packed, conflict-free contiguous reads). A-operands global->reg.
// c-states live in registers for the whole sequence. One grid.sync per slot.
// Slot s: layer0 computes step s, layer1 computes step s-1 (pipelined).
// ---------------------------------------------------------------------------
__global__ __launch_bounds__(512, 2) void lstm_persist(
    const float* __restrict__ X,
    const u16* __restrict__ Wp0, const u16* __restrict__ Wp1,
    const float* __restrict__ bih0, const float* __restrict__ bhh0,
    const float* __restrict__ bih1, const float* __restrict__ bhh1,
    u16* h0a, u16* h0b, u16* h1a, u16* h1b,
    float* __restrict__ latent)
{
    extern __shared__ u16 sW[];
    u16* sW1 = sW;            // 32768 u16
    u16* sW0 = sW + W1_U16;   // 20480 u16

    const int tid  = threadIdx.x;
    const int lane = tid & 63;
    const int w    = tid >> 6;           // wave 0..7
    const int mb   = (int)blockIdx.x & 15;
    const int nb   = (int)blockIdx.x >> 4;

    // one-time: copy this block's weight slices into LDS (linear 16B copies)
    {
        const int4* g1 = (const int4*)(Wp1 + (size_t)nb * W1_U16);
        int4* d1 = (int4*)sW1;
        for (int i = tid; i < W1_U16 / 8; i += 512) d1[i] = g1[i];
        const int4* g0 = (const int4*)(Wp0 + (size_t)nb * W0_U16);
        int4* d0 = (int4*)sW0;
        for (int i = tid; i < W0_U16 / 8; i += 512) d0[i] = g0[i];
    }

    const int ncol = nb * 16 + (lane & 15);        // output h column
    float bg0[4], bg1[4];
#pragma unroll
    for (int g = 0; g < 4; ++g) {
        bg0[g] = bih0[g * 256 + ncol] + bhh0[g * 256 + ncol];
        bg1[g] = bih1[g * 256 + ncol] + bhh1[g * 256 + ncol];
    }
    const int arow = mb * 128 + w * 16 + (lane & 15);   // A-frag row
    const int orow = mb * 128 + w * 16 + (lane >> 4) * 4; // C-frag row base
    const int kq8  = (lane >> 4) * 8;

    __syncthreads();
    cg::grid_group grid = cg::this_grid();

    u16* h0c = h0a; u16* h0n = h0b;
    u16* h1c = h1a; u16* h1n = h1b;
    f32x4 c0 = {0.f, 0.f, 0.f, 0.f};
    f32x4 c1 = {0.f, 0.f, 0.f, 0.f};

    for (int s = 0; s <= LSTM_L; ++s) {
        // ---- issue all A-fragment loads up front ----
        bf16x8 xf[2], hf0[8], hf1[8];
        if (s < LSTM_L) {
            const float* xs = X + (size_t)s * LSTM_B * LSTM_HIN
                                + (size_t)arow * LSTM_HIN + kq8;
#pragma unroll
            for (int f = 0; f < 2; ++f) {
                const float4 v0 = *(const float4*)(xs + f * 32);
                const float4 v1 = *(const float4*)(xs + f * 32 + 4);
                bf16x8 p;
                p[0] = (__bf16)v0.x; p[1] = (__bf16)v0.y;
                p[2] = (__bf16)v0.z; p[3] = (__bf16)v0.w;
                p[4] = (__bf16)v1.x; p[5] = (__bf16)v1.y;
                p[6] = (__bf16)v1.z; p[7] = (__bf16)v1.w;
                xf[f] = p;
            }
        }
#pragma unroll
        for (int f = 0; f < 8; ++f)
            hf0[f] = *(const bf16x8*)(h0c + (size_t)arow * 256 + f * 32 + kq8);
        if (s > 0) {
#pragma unroll
            for (int f = 0; f < 8; ++f)
                hf1[f] = *(const bf16x8*)(h1c + (size_t)arow * 256 + f * 32 + kq8);
        }

        // ---- layer 0, step s ----
        if (s < LSTM_L) {
            f32x4 acc[4] = {{0,0,0,0},{0,0,0,0},{0,0,0,0},{0,0,0,0}};
#pragma unroll
            for (int c = 0; c < NCH0; ++c) {
                const bf16x8 a = (c < 2) ? xf[c] : hf0[c - 2];
#pragma unroll
                for (int g = 0; g < 4; ++g) {
                    const bf16x8 b =
                        *(const bf16x8*)&sW0[((c * 4 + g) * 64 + lane) * 8];
                    acc[g] = __builtin_amdgcn_mfma_f32_16x16x32_bf16(
                        a, b, acc[g], 0, 0, 0);
                }
            }
#pragma unroll
            for (int r = 0; r < 4; ++r) {
                const float gi = acc[0][r] + bg0[0];
                const float gf = acc[1][r] + bg0[1];
                const float gg = acc[2][r] + bg0[2];
                const float go = acc[3][r] + bg0[3];
                const float si = 1.f / (1.f + expf(-gi));
                const float sf = 1.f / (1.f + expf(-gf));
                const float so = 1.f / (1.f + expf(-go));
                const float cn = sf * c0[r] + si * tanhf(gg);
                c0[r] = cn;
                const float hv = so * tanhf(cn);
                h0n[(size_t)(orow + r) * 256 + ncol] =
                    __builtin_bit_cast(u16, (__bf16)hv);
            }
        }

        // ---- layer 1, step s-1 ----
        if (s > 0) {
            f32x4 acc[4] = {{0,0,0,0},{0,0,0,0},{0,0,0,0},{0,0,0,0}};
#pragma unroll
            for (int c = 0; c < NCH1; ++c) {
                const bf16x8 a = (c < 8) ? hf0[c] : hf1[c - 8];
#pragma unroll
                for (int g = 0; g < 4; ++g) {
                    const bf16x8 b =
                        *(const bf16x8*)&sW1[((c * 4 + g) * 64 + lane) * 8];
                    acc[g] = __builtin_amdgcn_mfma_f32_16x16x32_bf16(
                        a, b, acc[g], 0, 0, 0);
                }
            }
#pragma unroll
            for (int r = 0; r < 4; ++r) {
                const float gi = acc[0][r] + bg1[0];
                const float gf = acc[1][r] + bg1[1];
                const float gg = acc[2][r] + bg1[2];
                const float go = acc[3][r] + bg1[3];
                const float si = 1.f / (1.f + expf(-gi));
                const float sf = 1.f / (1.f + expf(-gf));
                const float so = 1.f / (1.f + expf(-go));
                const float cn = sf * c1[r] + si * tanhf(gg);
                c1[r] = cn;
                const float hv = so * tanhf(cn);
                if (s == LSTM_L) {
                    latent[(size_t)(orow + r) * 256 + ncol] = hv;
                } else {
                    h1n[(size_t)(orow + r) * 256 + ncol] =
                        __builtin_bit_cast(u16, (__bf16)hv);
                }
            }
        }

        if (s < LSTM_L) grid.sync();
        if (s < LSTM_L) { u16* t = h0c; h0c = h0n; h0n = t; }
        if (s > 0)      { u16* t = h1c; h1c = h1n; h1n = t; }
    }
}

// ---------------------------------------------------------------------------
// K-means tail
// ---------------------------------------------------------------------------
__global__ __launch_bounds__(64) void assign_kernel(
    const float* __restrict__ lat, const float* __restrict__ clusters,
    int* __restrict__ ids)
{
    __shared__ float row[LSTM_H];
    const int b = blockIdx.x;
    const int k = threadIdx.x;
    for (int i = k; i < LSTM_H; i += 64) row[i] = lat[(size_t)b * LSTM_H + i];
    __syncthreads();
    const float* ck = clusters + (size_t)k * LSTM_H;
    float d = 0.f;
#pragma unroll 8
    for (int i = 0; i < LSTM_H; ++i) { const float t = row[i] - ck[i]; d += t * t; }
    int idx = k;
    for (int off = 32; off > 0; off >>= 1) {
        const float od = __shfl_down(d, off, 64);
        const int   oi = __shfl_down(idx, off, 64);
        if (od < d || (od == d && oi < idx)) { d = od; idx = oi; }
    }
    if (k == 0) ids[b] = idx;
}

__global__ __launch_bounds__(256) void centroid_kernel(
    const float* __restrict__ lat, const int* __restrict__ ids,
    const float* __restrict__ clusters, float* __restrict__ upd)
{
    __shared__ int sid[LSTM_B];
    const int k = blockIdx.x;
    const int h = threadIdx.x;
    for (int i = threadIdx.x; i < LSTM_B; i += 256) sid[i] = ids[i];
    __syncthreads();
    float s = 0.f;
    int cnt = 0;
    for (int b = 0; b < LSTM_B; ++b) {
        if (sid[b] == k) { s += lat[(size_t)b * LSTM_H + h]; cnt++; }
    }
    upd[(size_t)k * LSTM_H + h] =
        (cnt > 0) ? s / (float)cnt : clusters[(size_t)k * LSTM_H + h];
}

__global__ __launch_bounds__(256) void loss_kernel(
    const float* __restrict__ lat, const int* __restrict__ ids,
    const float* __restrict__ upd, float* __restrict__ out_loss)
{
    float p = 0.f;
    const int total = LSTM_B * LSTM_H;
    for (int idx = blockIdx.x * blockDim.x + threadIdx.x; idx < total;
         idx += gridDim.x * blockDim.x) {
        const int b = idx >> 8;
        const float d = lat[idx] - upd[(size_t)ids[b] * LSTM_H + (idx & 255)];
        p += d * d;
    }
    for (int off = 32; off > 0; off >>= 1) p += __shfl_down(p, off, 64);
    __shared__ float wsum[4];
    const int lane = threadIdx.x & 63, wid = threadIdx.x >> 6;
    if (lane == 0) wsum[wid] = p;
    __syncthreads();
    if (threadIdx.x == 0)
        atomicAdd(out_loss, HALF_BETA * (wsum[0] + wsum[1] + wsum[2] + wsum[3]));
}

// ---------------------------------------------------------------------------
extern "C" void kernel_launch(void* const* d_in, const int* in_sizes, int n_in,
                              void* d_out, int out_size, void* d_ws, size_t ws_size,
                              hipStream_t stream)
{
    const float* X     = (const float*)d_in[0];
    const float* Wih0  = (const float*)d_in[1];
    const float* Whh0  = (const float*)d_in[2];
    const float* bih0  = (const float*)d_in[3];
    const float* bhh0  = (const float*)d_in[4];
    const float* Wih1  = (const float*)d_in[5];
    const float* Whh1  = (const float*)d_in[6];
    const float* bih1  = (const float*)d_in[7];
    const float* bhh1  = (const float*)d_in[8];
    const float* clust = (const float*)d_in[9];

    float* out = (float*)d_out;
    char* base = (char*)d_ws;
    const size_t MB = 1u << 20;

    u16* Wp0   = (u16*)(base + 0 * MB);          // 640 KB
    u16* Wp1   = (u16*)(base + 1 * MB);          // 1 MB
    u16* h0a   = (u16*)(base + 2 * MB);          // 1 MB each
    u16* h0b   = (u16*)(base + 3 * MB);
    u16* h1a   = (u16*)(base + 4 * MB);
    u16* h1b   = (u16*)(base + 5 * MB);
    float* upd = (float*)(base + 6 * MB);        // 64 KB
    int* ids   = (int*)(base + 6 * MB + 256 * 1024);

    const size_t BH = (size_t)LSTM_B * LSTM_H;

    hipMemsetAsync(h0a, 0, MB, stream);
    hipMemsetAsync(h1a, 0, MB, stream);
    hipMemsetAsync(out + BH, 0, sizeof(float), stream);

    pack_frag<LSTM_HIN><<<320, 256, 0, stream>>>(Wih0, Whh0, Wp0);
    pack_frag<LSTM_H>  <<<512, 256, 0, stream>>>(Wih1, Whh1, Wp1);

    hipFuncSetAttribute((const void*)lstm_persist,
                        hipFuncAttributeMaxDynamicSharedMemorySize, LDS_BYTES);

    float* lat = out;
    void* args[] = {
        (void*)&X, (void*)&Wp0, (void*)&Wp1,
        (void*)&bih0, (void*)&bhh0, (void*)&bih1, (void*)&bhh1,
        (void*)&h0a, (void*)&h0b, (void*)&h1a, (void*)&h1b, (void*)&lat
    };
    hipLaunchCooperativeKernel((void*)lstm_persist, dim3(256), dim3(512),
                               args, LDS_BYTES, stream);

    assign_kernel<<<LSTM_B, 64, 0, stream>>>(out, clust, ids);
    centroid_kernel<<<NCLUST, 256, 0, stream>>>(out, ids, clust, upd);
    loss_kernel<<<256, 256, 0, stream>>>(out, ids, upd, out + BH);
}

// Round 4
// 3184.471 us; speedup vs baseline: 2.5286x; 2.5286x over previous
//
#include <hip/hip_runtime.h>
#include <hip/hip_bf16.h>
#include <math.h>

typedef unsigned short u16;
typedef __attribute__((ext_vector_type(8))) __bf16 bf16x8;
typedef __attribute__((ext_vector_type(4))) float f32x4;

#define LSTM_L 200
#define LSTM_B 2048
#define LSTM_HIN 64
#define LSTM_H 256
#define NCLUST 64
#define HALF_BETA 0.05f
#define LDS_BYTES 131072

__device__ __forceinline__ void gload_lds16(const void* g, void* l) {
    __builtin_amdgcn_global_load_lds(
        (__attribute__((address_space(1))) const void*)g,
        (__attribute__((address_space(3))) void*)l, 16, 0, 0);
}

__device__ __forceinline__ float fast_sigmoid(float x) {
    return __builtin_amdgcn_rcpf(1.f + __expf(-x));
}
__device__ __forceinline__ float fast_tanh(float x) {
    return 2.f * __builtin_amdgcn_rcpf(1.f + __expf(-2.f * x)) - 1.f;
}

// ---------------------------------------------------------------------------
// Weight pack into per-(nb,wn) fragment order:
// i = ((((nb*4+wn)*NCH + ch)*2 + nf)*64 + lane)*8 + e
// j = (2*nf + (l15&1))*256 + nb*32 + wn*8 + (l15>>1)   [gate*256 + hcol]
// k = ch*32 + (lane>>4)*8 + e;  W = [Wih | Whh] k-concat, bf16.
// ---------------------------------------------------------------------------
template<int KIN>
__global__ __launch_bounds__(256) void pack_frag(
    const float* __restrict__ Wih, const float* __restrict__ Whh,
    u16* __restrict__ Wp)
{
    constexpr int NCH = (KIN + LSTM_H) / 32;
    const int total = 1024 * (KIN + LSTM_H);
    for (int i = blockIdx.x * 256 + threadIdx.x; i < total; i += gridDim.x * 256) {
        const int e = i & 7;
        int t = i >> 3;
        const int lane = t & 63; t >>= 6;
        const int nf = t & 1;    t >>= 1;
        const int ch = t % NCH;  t /= NCH;
        const int wn = t & 3;
        const int nb = t >> 2;
        const int l15 = lane & 15;
        const int j = (2 * nf + (l15 & 1)) * 256 + nb * 32 + wn * 8 + (l15 >> 1);
        const int k = ch * 32 + ((lane >> 4) << 3) + e;
        const float v = (k < KIN) ? Wih[(size_t)j * KIN + k]
                                  : Whh[(size_t)j * LSTM_H + (k - KIN)];
        Wp[i] = __builtin_bit_cast(u16, (__bf16)v);
    }
}

// ---------------------------------------------------------------------------
// One layer step. Block = 128 rows x 128 gatecols; 8 waves (2m x 4n);
// wave = 64 rows x 32 cols (4 m-frags x 2 n-frags of 16x16x32 bf16 MFMA).
// B (weights) in VGPRs, loaded once from frag-packed Wp. A staged to LDS once
// (XOR-swizzled), then a barrier-free fully-unrolled K loop.
// Col mapping: lane l15 -> hcol = nb*32 + wn*8 + (l15>>1); nf0 gates {i,f},
// nf1 gates {g,o}, gate parity = l15&1 -> pointwise via 2x shfl_xor(1).
// ---------------------------------------------------------------------------
template<int KIN>
__device__ __forceinline__ void run_layer(
    const float* __restrict__ xf32,     // L0: X slice (f32), else nullptr
    const u16* __restrict__ hbelow,     // L1: h0 current; L0: unused
    const u16* __restrict__ hself,      // recurrent hidden (bf16)
    const u16* __restrict__ Wp,
    const float* __restrict__ bih, const float* __restrict__ bhh,
    u16* __restrict__ hout, float* __restrict__ latout,
    float* __restrict__ cst,
    int blk, char* smem, int tid)
{
    constexpr int NCH = (KIN + LSTM_H) / 32;
    constexpr bool IS_L0 = (KIN == 64);
    const int lane = tid & 63;
    const int w = tid >> 6;
    const int wm = w >> 2;            // 0..1
    const int wn = w & 3;             // 0..3
    const int l15 = lane & 15;
    const int q = lane >> 4;          // 0..3
    const int mb = blk >> 3;
    const int nb = blk & 7;
    const int b0 = mb * 128;

    // ---- B into registers (frag-packed, contiguous 16B loads) ----
    bf16x8 Breg[NCH][2];
    {
        const u16* wp = Wp + (size_t)((nb * 4 + wn) * NCH) * 1024 + lane * 8;
#pragma unroll
        for (int ch = 0; ch < NCH; ++ch)
#pragma unroll
            for (int nf = 0; nf < 2; ++nf)
                Breg[ch][nf] = *(const bf16x8*)(wp + (ch * 2 + nf) * 512);
    }

    // ---- c-state preload ----
    const int hcol = nb * 32 + wn * 8 + (l15 >> 1);
    const int rowA = wm * 64;
    float cp[4][4];
#pragma unroll
    for (int mf = 0; mf < 4; ++mf)
#pragma unroll
        for (int r = 0; r < 4; ++r)
            cp[mf][r] = cst[(size_t)(b0 + rowA + mf * 16 + q * 4 + r) * 256 + hcol];

    // ---- bias ----
    const int gpar = l15 & 1;
    const float b0a = bih[gpar * 256 + hcol] + bhh[gpar * 256 + hcol];
    const float b1a = bih[(2 + gpar) * 256 + hcol] + bhh[(2 + gpar) * 256 + hcol];

    // ---- stage A into LDS (swizzled source, linear dest) ----
    if (IS_L0) {
        // H region: [128 rows][512 B] at 0, via global_load_lds
#pragma unroll
        for (int i = 0; i < 8; ++i) {
            const int slot = i * 512 + tid;
            const int row = slot >> 5;
            const int so = (slot & 31) * 16;
            const int koff = so ^ ((row & 7) << 4);
            gload_lds16((const char*)hself + (size_t)(b0 + row) * 512 + koff,
                        smem + slot * 16);
        }
        // X region: [128 rows][128 B] at 65536, reg-convert f32->bf16
#pragma unroll
        for (int p = 0; p < 2; ++p) {
            const int slot = p * 512 + tid;
            const int row = slot >> 3;
            const int so = (slot & 7) * 16;
            const int koff = so ^ ((row & 7) << 4);
            const float* s = xf32 + (size_t)(b0 + row) * 64 + (koff >> 1);
            const float4 v0 = *(const float4*)s;
            const float4 v1 = *(const float4*)(s + 4);
            bf16x8 pk;
            pk[0] = (__bf16)v0.x; pk[1] = (__bf16)v0.y;
            pk[2] = (__bf16)v0.z; pk[3] = (__bf16)v0.w;
            pk[4] = (__bf16)v1.x; pk[5] = (__bf16)v1.y;
            pk[6] = (__bf16)v1.z; pk[7] = (__bf16)v1.w;
            *(bf16x8*)(smem + 65536 + slot * 16) = pk;
        }
    } else {
        // single region: [128 rows][1024 B]: first 512 = hbelow, rest = hself
#pragma unroll
        for (int i = 0; i < 16; ++i) {
            const int slot = i * 512 + tid;
            const int row = slot >> 6;
            const int so = (slot & 63) * 16;
            const int koff = so ^ ((row & 7) << 4);
            const char* src = (koff < 512)
                ? (const char*)hbelow + (size_t)(b0 + row) * 512 + koff
                : (const char*)hself + (size_t)(b0 + row) * 512 + (koff - 512);
            gload_lds16(src, smem + slot * 16);
        }
    }
    __syncthreads();

    // ---- barrier-free K loop ----
    f32x4 acc[4][2];
#pragma unroll
    for (int mf = 0; mf < 4; ++mf)
#pragma unroll
        for (int nf = 0; nf < 2; ++nf) acc[mf][nf] = f32x4{0.f, 0.f, 0.f, 0.f};

    const int qoff = q * 16;
    const int swzl = (l15 & 7) << 4;
#pragma unroll
    for (int ch = 0; ch < NCH; ++ch) {
        bf16x8 af[4];
#pragma unroll
        for (int mf = 0; mf < 4; ++mf) {
            const int row = rowA + mf * 16 + l15;
            const char* ap;
            if (IS_L0) {
                if (ch < 2)
                    ap = smem + 65536 + row * 128 + ((ch * 64 + qoff) ^ swzl);
                else
                    ap = smem + row * 512 + (((ch - 2) * 64 + qoff) ^ swzl);
            } else {
                ap = smem + row * 1024 + ((ch * 64 + qoff) ^ swzl);
            }
            af[mf] = *(const bf16x8*)ap;
        }
#pragma unroll
        for (int mf = 0; mf < 4; ++mf)
#pragma unroll
            for (int nf = 0; nf < 2; ++nf)
                acc[mf][nf] = __builtin_amdgcn_mfma_f32_16x16x32_bf16(
                    af[mf], Breg[ch][nf], acc[mf][nf], 0, 0, 0);
    }

    // ---- pointwise epilogue: gather 4 gates via 2 shfl_xor(1) ----
#pragma unroll
    for (int mf = 0; mf < 4; ++mf) {
#pragma unroll
        for (int r = 0; r < 4; ++r) {
            const float a0 = acc[mf][0][r] + b0a;
            const float a1 = acc[mf][1][r] + b1a;
            const float p0 = __shfl_xor(a0, 1);
            const float p1 = __shfl_xor(a1, 1);
            const float gi = gpar ? p0 : a0;
            const float gf = gpar ? a0 : p0;
            const float gg = gpar ? p1 : a1;
            const float go = gpar ? a1 : p1;
            const float cn = fast_sigmoid(gf) * cp[mf][r]
                           + fast_sigmoid(gi) * fast_tanh(gg);
            const float hv = fast_sigmoid(go) * fast_tanh(cn);
            const size_t oidx =
                (size_t)(b0 + rowA + mf * 16 + q * 4 + r) * 256 + hcol;
            if (gpar) {
                cst[oidx] = cn;                       // odd lane: c-state
            } else if (latout) {
                latout[oidx] = hv;                    // final slot: f32 latent
            } else {
                hout[oidx] = __builtin_bit_cast(u16, (__bf16)hv);
            }
        }
    }
}

// Slot s: blocks 0..127 -> layer0 step s; 128..255 -> layer1 step s-1.
__global__ __launch_bounds__(512, 2) void lstm_slot(
    const float* __restrict__ xt,
    const u16* __restrict__ h0c, u16* __restrict__ h0n, float* __restrict__ c0,
    const u16* __restrict__ Wp0,
    const float* __restrict__ bih0, const float* __restrict__ bhh0,
    const u16* __restrict__ h1c, u16* __restrict__ h1n, float* __restrict__ c1,
    const u16* __restrict__ Wp1,
    const float* __restrict__ bih1, const float* __restrict__ bhh1,
    float* __restrict__ latout, int do0, int do1)
{
    extern __shared__ char smem[];
    const int tid = threadIdx.x;
    if (blockIdx.x < 128) {
        if (do0)
            run_layer<LSTM_HIN>(xt, nullptr, h0c, Wp0, bih0, bhh0,
                                h0n, nullptr, c0, blockIdx.x, smem, tid);
    } else {
        if (do1)
            run_layer<LSTM_H>(nullptr, h0c, h1c, Wp1, bih1, bhh1,
                              h1n, latout, c1, blockIdx.x - 128, smem, tid);
    }
}

// ---------------------------------------------------------------------------
// K-means tail
// ---------------------------------------------------------------------------
__global__ __launch_bounds__(64) void assign_kernel(
    const float* __restrict__ lat, const float* __restrict__ clusters,
    int* __restrict__ ids)
{
    __shared__ float row[LSTM_H];
    const int b = blockIdx.x;
    const int k = threadIdx.x;
    for (int i = k; i < LSTM_H; i += 64) row[i] = lat[(size_t)b * LSTM_H + i];
    __syncthreads();
    const float* ck = clusters + (size_t)k * LSTM_H;
    float d = 0.f;
#pragma unroll 8
    for (int i = 0; i < LSTM_H; ++i) { const float t = row[i] - ck[i]; d += t * t; }
    int idx = k;
    for (int off = 32; off > 0; off >>= 1) {
        const float od = __shfl_down(d, off, 64);
        const int   oi = __shfl_down(idx, off, 64);
        if (od < d || (od == d && oi < idx)) { d = od; idx = oi; }
    }
    if (k == 0) ids[b] = idx;
}

__global__ __launch_bounds__(256) void centroid_kernel(
    const float* __restrict__ lat, const int* __restrict__ ids,
    const float* __restrict__ clusters, float* __restrict__ upd)
{
    __shared__ int sid[LSTM_B];
    const int k = blockIdx.x;
    const int h = threadIdx.x;
    for (int i = threadIdx.x; i < LSTM_B; i += 256) sid[i] = ids[i];
    __syncthreads();
    float s = 0.f;
    int cnt = 0;
    for (int b = 0; b < LSTM_B; ++b) {
        if (sid[b] == k) { s += lat[(size_t)b * LSTM_H + h]; cnt++; }
    }
    upd[(size_t)k * LSTM_H + h] =
        (cnt > 0) ? s / (float)cnt : clusters[(size_t)k * LSTM_H + h];
}

__global__ __launch_bounds__(256) void loss_kernel(
    const float* __restrict__ lat, const int* __restrict__ ids,
    const float* __restrict__ upd, float* __restrict__ out_loss)
{
    float p = 0.f;
    const int total = LSTM_B * LSTM_H;
    for (int idx = blockIdx.x * blockDim.x + threadIdx.x; idx < total;
         idx += gridDim.x * blockDim.x) {
        const int b = idx >> 8;
        const float d = lat[idx] - upd[(size_t)ids[b] * LSTM_H + (idx & 255)];
        p += d * d;
    }
    for (int off = 32; off > 0; off >>= 1) p += __shfl_down(p, off, 64);
    __shared__ float wsum[4];
    const int lane = threadIdx.x & 63, wid = threadIdx.x >> 6;
    if (lane == 0) wsum[wid] = p;
    __syncthreads();
    if (threadIdx.x == 0)
        atomicAdd(out_loss, HALF_BETA * (wsum[0] + wsum[1] + wsum[2] + wsum[3]));
}

// ---------------------------------------------------------------------------
extern "C" void kernel_launch(void* const* d_in, const int* in_sizes, int n_in,
                              void* d_out, int out_size, void* d_ws, size_t ws_size,
                              hipStream_t stream)
{
    const float* X     = (const float*)d_in[0];
    const float* Wih0  = (const float*)d_in[1];
    const float* Whh0  = (const float*)d_in[2];
    const float* bih0  = (const float*)d_in[3];
    const float* bhh0  = (const float*)d_in[4];
    const float* Wih1  = (const float*)d_in[5];
    const float* Whh1  = (const float*)d_in[6];
    const float* bih1  = (const float*)d_in[7];
    const float* bhh1  = (const float*)d_in[8];
    const float* clust = (const float*)d_in[9];

    float* out = (float*)d_out;
    char* base = (char*)d_ws;
    const size_t MB = 1u << 20;

    u16* Wp0   = (u16*)(base + 0 * MB);          // 640 KB
    u16* Wp1   = (u16*)(base + 1 * MB);          // 1 MB
    u16* h0a   = (u16*)(base + 2 * MB);          // 1 MB each
    u16* h0b   = (u16*)(base + 3 * MB);
    u16* h1a   = (u16*)(base + 4 * MB);
    u16* h1b   = (u16*)(base + 5 * MB);
    float* c0  = (float*)(base + 6 * MB);        // 2 MB
    float* c1  = (float*)(base + 8 * MB);        // 2 MB
    float* upd = (float*)(base + 10 * MB);       // 64 KB
    int* ids   = (int*)(base + 10 * MB + 256 * 1024);

    const size_t BH = (size_t)LSTM_B * LSTM_H;

    hipMemsetAsync(h0a, 0, MB, stream);
    hipMemsetAsync(h1a, 0, MB, stream);
    hipMemsetAsync(c0, 0, 4 * MB, stream);       // c0+c1 contiguous
    hipMemsetAsync(out + BH, 0, sizeof(float), stream);

    pack_frag<LSTM_HIN><<<320, 256, 0, stream>>>(Wih0, Whh0, Wp0);
    pack_frag<LSTM_H>  <<<512, 256, 0, stream>>>(Wih1, Whh1, Wp1);

    hipFuncSetAttribute((const void*)lstm_slot,
                        hipFuncAttributeMaxDynamicSharedMemorySize, LDS_BYTES);

    u16* h0c = h0a; u16* h0n = h0b;
    u16* h1c = h1a; u16* h1n = h1b;
    for (int s = 0; s <= LSTM_L; ++s) {
        const int do0 = (s < LSTM_L) ? 1 : 0;
        const int do1 = (s > 0) ? 1 : 0;
        const float* xt = do0 ? X + (size_t)s * LSTM_B * LSTM_HIN : nullptr;
        float* lat = (s == LSTM_L) ? out : nullptr;
        lstm_slot<<<256, 512, LDS_BYTES, stream>>>(
            xt, h0c, h0n, c0, Wp0, bih0, bhh0,
            h1c, h1n, c1, Wp1, bih1, bhh1, lat, do0, do1);
        if (do0) { u16* t = h0c; h0c = h0n; h0n = t; }
        if (do1) { u16* t = h1c; h1c = h1n; h1n = t; }
    }

    assign_kernel<<<LSTM_B, 64, 0, stream>>>(out, clust, ids);
    centroid_kernel<<<NCLUST, 256, 0, stream>>>(out, ids, clust, upd);
    loss_kernel<<<256, 256, 0, stream>>>(out, ids, upd, out + BH);
}